// Round 5
// baseline (322.020 us; speedup 1.0000x reference)
//
#include <hip/hip_runtime.h>

#define D 64
#define D4 (D / 4)         // 16 float4 per fp32 row

typedef float f32x4 __attribute__((ext_vector_type(4)));

__device__ __forceinline__ float elu1(float z) {
    return z > 0.0f ? z : expm1f(z);
}

// pack two fp32 -> bf16 pair (RNE), a in low 16, b in high 16
__device__ __forceinline__ unsigned int bfpair(float a, float b) {
    unsigned int ua = __float_as_uint(a);
    unsigned int ub = __float_as_uint(b);
    ua = (ua + 0x7FFFu + ((ua >> 16) & 1u)) >> 16;
    ub = (ub + 0x7FFFu + ((ub >> 16) & 1u)) & 0xFFFF0000u;
    return ub | ua;
}

__device__ __forceinline__ float bl16(int u) {
    return __uint_as_float((unsigned)u << 16);
}
__device__ __forceinline__ float bh16(int u) {
    return __uint_as_float((unsigned)u & 0xFFFF0000u);
}

// ---------- K1: emb16 = bf16(elu(x*w)); also zeroes node_deg for K2 ----------
__global__ void emb_kernel(const float* __restrict__ x,
                           const float* __restrict__ w,
                           uint4* __restrict__ emb16,
                           int* __restrict__ node_deg,
                           int total8, int n_nodes) {
    int i = blockIdx.x * blockDim.x + threadIdx.x;
    if (i < n_nodes) node_deg[i] = 0;
    if (i >= total8) return;
    f32x4 a = __builtin_nontemporal_load((const f32x4*)x + 2 * i);
    f32x4 b = __builtin_nontemporal_load((const f32x4*)x + 2 * i + 1);
    float4 wa = ((const float4*)w)[(2 * i) & 15];
    float4 wb = ((const float4*)w)[(2 * i + 1) & 15];
    uint4 o;
    o.x = bfpair(elu1(a.x * wa.x), elu1(a.y * wa.y));
    o.y = bfpair(elu1(a.z * wa.z), elu1(a.w * wa.w));
    o.z = bfpair(elu1(b.x * wb.x), elu1(b.y * wb.y));
    o.w = bfpair(elu1(b.z * wb.z), elu1(b.w * wb.w));
    emb16[i] = o;
}

// ---------- K2: edge-parallel degree histogram (global atomics, L2-resident) --
__global__ void hist_kernel(const int* __restrict__ dst,
                            int* __restrict__ node_deg, int n_edges) {
    int i = blockIdx.x * blockDim.x + threadIdx.x;
    const int n4 = n_edges >> 2;
    if (i < n4) {
        int4 dv = ((const int4*)dst)[i];
        atomicAdd(&node_deg[dv.x], 1);
        atomicAdd(&node_deg[dv.y], 1);
        atomicAdd(&node_deg[dv.z], 1);
        atomicAdd(&node_deg[dv.w], 1);
    }
    if (i < (n_edges & 3))
        atomicAdd(&node_deg[dst[(n4 << 2) + i]], 1);
}

// ---------- K3a: per-block (512 nodes) exclusive scan; e0 -> node_off, total -> bsum
__global__ __launch_bounds__(512) void scan_block_kernel(
        const int* __restrict__ node_deg,
        int* __restrict__ node_off,
        int* __restrict__ bsum, int n_nodes) {
    __shared__ int wsum[8];
    const int tid = threadIdx.x, lane = tid & 63, wid = tid >> 6;
    const int g = blockIdx.x * 512 + tid;
    int v = (g < n_nodes) ? node_deg[g] : 0;
    int incl = v;
    #pragma unroll
    for (int off = 1; off < 64; off <<= 1) {
        int t = __shfl_up(incl, off, 64);
        if (lane >= off) incl += t;
    }
    if (lane == 63) wsum[wid] = incl;
    __syncthreads();
    int pre = 0;
    for (int k = 0; k < wid; k++) pre += wsum[k];
    if (g < n_nodes) node_off[g] = pre + incl - v;
    if (tid == 511) bsum[blockIdx.x] = pre + incl;
}

// ---------- K3b: add block base (redundant per-block prefix of bsum); cur init
__global__ __launch_bounds__(512) void scan_add_kernel(
        const int* __restrict__ bsum,
        int* __restrict__ node_off,
        int* __restrict__ cur, int n_nodes, int NBLK) {
    __shared__ int sbase;
    const int b = blockIdx.x, tid = threadIdx.x;
    if (tid < 64) {
        int p = 0;
        for (int k = tid; k < b; k += 64) p += bsum[k];
        #pragma unroll
        for (int off = 1; off < 64; off <<= 1) p += __shfl_xor(p, off, 64);
        if (tid == 0) sbase = p;
    }
    __syncthreads();
    const int base = sbase;
    const int g = b * 512 + tid;
    if (g < n_nodes) {
        int t = node_off[g] + base;
        node_off[g] = t;
        cur[g] = t;
    }
    if (b == NBLK - 1 && tid == 0)
        node_off[n_nodes] = base + bsum[b];
}

// ---------- K4: edge-parallel counting-sort scatter -> sorted2 (CSR adj) ------
__global__ void scatter_sort_kernel(const int* __restrict__ src,
                                    const int* __restrict__ dst,
                                    int* __restrict__ cur,
                                    int* __restrict__ sorted2, int n_edges) {
    int i = blockIdx.x * blockDim.x + threadIdx.x;
    const int n4 = n_edges >> 2;
    if (i < n4) {
        int4 dv = ((const int4*)dst)[i];
        int4 sv = ((const int4*)src)[i];
        int p;
        p = atomicAdd(&cur[dv.x], 1); sorted2[p] = sv.x;
        p = atomicAdd(&cur[dv.y], 1); sorted2[p] = sv.y;
        p = atomicAdd(&cur[dv.z], 1); sorted2[p] = sv.z;
        p = atomicAdd(&cur[dv.w], 1); sorted2[p] = sv.w;
    }
    if (i < (n_edges & 3)) {
        int k = (n4 << 2) + i;
        int p = atomicAdd(&cur[dst[k]], 1);
        sorted2[p] = src[k];
    }
}

// ---------- K5: wave per node; coalesced index preload + shfl broadcast; up to
//               4 row-gathers in flight per group ----------
__global__ void gather_sum_kernel(const unsigned int* __restrict__ emb16,
                                  const int* __restrict__ sorted2,
                                  const int* __restrict__ node_off,
                                  float* __restrict__ out, int n_nodes) {
    int wave = (blockIdx.x * blockDim.x + threadIdx.x) >> 6;
    if (wave >= n_nodes) return;
    const int lane = threadIdx.x & 63;
    const int g = lane >> 3;          // 8 edge slots
    const int c = lane & 7;           // 8 int4-chunks per 128B row
    const int beg = node_off[wave], end = node_off[wave + 1];
    const int deg = end - beg;
    const int dmain = min(deg, 64);
    const int4* row = (const int4*)emb16;   // 8 int4 per row

    // one coalesced 64-lane load grabs this node's whole index list
    int myidx = 0;
    if (lane < dmain) myidx = __builtin_nontemporal_load(sorted2 + beg + lane);

    float acc[8] = {0.f, 0.f, 0.f, 0.f, 0.f, 0.f, 0.f, 0.f};

    for (int base = 0; base < dmain; base += 32) {
        const int m = dmain - base;   // edges remaining in this 32-round
        int s0 = __shfl(myidx, base + g, 64);
        int s1 = __shfl(myidx, base + g + 8, 64);
        int s2 = __shfl(myidx, base + g + 16, 64);
        int s3 = __shfl(myidx, base + g + 24, 64);
        int4 u0 = make_int4(0, 0, 0, 0);
        int4 u1 = make_int4(0, 0, 0, 0);
        int4 u2 = make_int4(0, 0, 0, 0);
        int4 u3 = make_int4(0, 0, 0, 0);
        // load phase: up to 4 independent gathers in flight per group
        if (g < m)      u0 = row[s0 * 8 + c];
        if (g + 8 < m)  u1 = row[s1 * 8 + c];
        if (g + 16 < m) u2 = row[s2 * 8 + c];
        if (g + 24 < m) u3 = row[s3 * 8 + c];
        // accumulate phase (zeros are numeric no-ops for masked slots)
        acc[0] += bl16(u0.x) + bl16(u1.x) + bl16(u2.x) + bl16(u3.x);
        acc[1] += bh16(u0.x) + bh16(u1.x) + bh16(u2.x) + bh16(u3.x);
        acc[2] += bl16(u0.y) + bl16(u1.y) + bl16(u2.y) + bl16(u3.y);
        acc[3] += bh16(u0.y) + bh16(u1.y) + bh16(u2.y) + bh16(u3.y);
        acc[4] += bl16(u0.z) + bl16(u1.z) + bl16(u2.z) + bl16(u3.z);
        acc[5] += bh16(u0.z) + bh16(u1.z) + bh16(u2.z) + bh16(u3.z);
        acc[6] += bl16(u0.w) + bl16(u1.w) + bl16(u2.w) + bl16(u3.w);
        acc[7] += bh16(u0.w) + bh16(u1.w) + bh16(u2.w) + bh16(u3.w);
    }
    // rare tail: deg > 64
    for (int e = beg + 64 + g; e < end; e += 8) {
        int s0 = __builtin_nontemporal_load(sorted2 + e);
        int4 u0 = row[s0 * 8 + c];
        acc[0] += bl16(u0.x); acc[1] += bh16(u0.x);
        acc[2] += bl16(u0.y); acc[3] += bh16(u0.y);
        acc[4] += bl16(u0.z); acc[5] += bh16(u0.z);
        acc[6] += bl16(u0.w); acc[7] += bh16(u0.w);
    }
    #pragma unroll
    for (int off = 8; off <= 32; off <<= 1) {
        #pragma unroll
        for (int k = 0; k < 8; k++) acc[k] += __shfl_xor(acc[k], off, 64);
    }
    if (g == 0) {
        f32x4* out4 = (f32x4*)out;
        f32x4 o0 = {acc[0], acc[1], acc[2], acc[3]};
        f32x4 o1 = {acc[4], acc[5], acc[6], acc[7]};
        __builtin_nontemporal_store(o0, out4 + wave * D4 + c * 2);
        __builtin_nontemporal_store(o1, out4 + wave * D4 + c * 2 + 1);
    }
}

// ---------- Fallback: atomic scatter ----------
__global__ void zero_out_kernel(float* __restrict__ out, int total4) {
    int i = blockIdx.x * blockDim.x + threadIdx.x;
    if (i < total4) ((float4*)out)[i] = make_float4(0.f, 0.f, 0.f, 0.f);
}

__global__ void scatter_fused_kernel(const float* __restrict__ x,
                                     const float* __restrict__ w,
                                     const int* __restrict__ src,
                                     const int* __restrict__ dst,
                                     float* __restrict__ out, int n_edges) {
    int t = blockIdx.x * blockDim.x + threadIdx.x;
    int e = t >> 4;
    int c = t & 15;
    if (e >= n_edges) return;
    int s = src[e];
    int d = dst[e];
    float4 xv = ((const float4*)x)[s * D4 + c];
    float4 wv = ((const float4*)w)[c];
    float* o = out + d * D + c * 4;
    unsafeAtomicAdd(o + 0, elu1(xv.x * wv.x));
    unsafeAtomicAdd(o + 1, elu1(xv.y * wv.y));
    unsafeAtomicAdd(o + 2, elu1(xv.z * wv.z));
    unsafeAtomicAdd(o + 3, elu1(xv.w * wv.w));
}

extern "C" void kernel_launch(void* const* d_in, const int* in_sizes, int n_in,
                              void* d_out, int out_size, void* d_ws, size_t ws_size,
                              hipStream_t stream) {
    const float* x   = (const float*)d_in[0];   // [N, 64] fp32
    const float* w   = (const float*)d_in[1];   // [1, 64] fp32
    const int*   src = (const int*)d_in[2];     // [E] int32
    const int*   dst = (const int*)d_in[3];     // [E] int32
    float* out = (float*)d_out;

    const int n_nodes = in_sizes[0] / D;
    const int n_edges = in_sizes[2];
    const int total4  = n_nodes * D4;
    const int total8  = n_nodes * 8;
    const int block = 256;

    const int NBLK = (n_nodes + 511) >> 9;      // 512-node scan blocks

    auto align16 = [](size_t v) { return (v + 15) & ~size_t(15); };
    const size_t emb_b      = align16((size_t)n_nodes * D * 2);          // bf16
    const size_t sorted2_b  = align16((size_t)n_edges * 4);
    const size_t nodeoff_b  = align16((size_t)(n_nodes + 1) * 4);
    const size_t deg_b      = align16((size_t)n_nodes * 4);
    const size_t cur_b      = align16((size_t)n_nodes * 4);
    const size_t bsum_b     = align16((size_t)NBLK * 4);
    const size_t need = emb_b + sorted2_b + nodeoff_b + deg_b + cur_b + bsum_b;

    if (ws_size >= need) {
        char* p = (char*)d_ws;
        unsigned int* emb16 = (unsigned int*)p;  p += emb_b;
        int* sorted2  = (int*)p;  p += sorted2_b;
        int* node_off = (int*)p;  p += nodeoff_b;
        int* node_deg = (int*)p;  p += deg_b;
        int* cur      = (int*)p;  p += cur_b;
        int* bsum     = (int*)p;

        emb_kernel<<<(total8 + block - 1) / block, block, 0, stream>>>(
            x, w, (uint4*)emb16, node_deg, total8, n_nodes);
        const int e4blk = ((n_edges >> 2) + block) / block + 1;
        hist_kernel<<<e4blk, block, 0, stream>>>(dst, node_deg, n_edges);
        scan_block_kernel<<<NBLK, 512, 0, stream>>>(
            node_deg, node_off, bsum, n_nodes);
        scan_add_kernel<<<NBLK, 512, 0, stream>>>(
            bsum, node_off, cur, n_nodes, NBLK);
        scatter_sort_kernel<<<e4blk, block, 0, stream>>>(
            src, dst, cur, sorted2, n_edges);
        const int wave_blocks = (n_nodes * 64 + block - 1) / block;
        gather_sum_kernel<<<wave_blocks, block, 0, stream>>>(
            emb16, sorted2, node_off, out, n_nodes);
    } else {
        zero_out_kernel<<<(total4 + block - 1) / block, block, 0, stream>>>(out, total4);
        const int nt = n_edges * 16;
        scatter_fused_kernel<<<(nt + block - 1) / block, block, 0, stream>>>(
            x, w, src, dst, out, n_edges);
    }
}

// Round 6
// 149.742 us; speedup vs baseline: 2.1505x; 2.1505x over previous
//
#include <hip/hip_runtime.h>

#define D 64
#define D4 (D / 4)         // 16 float4 per fp32 row
#define SBSHIFT 9          // 512 nodes per super-bucket
#define SBROWS 512
#define CHUNK_E 8192       // edges per chunk_sort block
#define STAGE_CAP 8704     // fine_sort staging entries (mean ~8163, +6 sigma)
#define NCH_MAX 256
#define NSB_MAX 256

typedef float f32x4 __attribute__((ext_vector_type(4)));

__device__ __forceinline__ float elu1(float z) {
    return z > 0.0f ? z : expm1f(z);
}

// pack two fp32 -> bf16 pair (RNE), a in low 16, b in high 16
__device__ __forceinline__ unsigned int bfpair(float a, float b) {
    unsigned int ua = __float_as_uint(a);
    unsigned int ub = __float_as_uint(b);
    ua = (ua + 0x7FFFu + ((ua >> 16) & 1u)) >> 16;
    ub = (ub + 0x7FFFu + ((ub >> 16) & 1u)) & 0xFFFF0000u;
    return ub | ua;
}

__device__ __forceinline__ float bl16(int u) {
    return __uint_as_float((unsigned)u << 16);
}
__device__ __forceinline__ float bh16(int u) {
    return __uint_as_float((unsigned)u & 0xFFFF0000u);
}

// ---------- K1: fused emb (grid-stride phase 0) + per-chunk LDS bucket sort ---
__global__ __launch_bounds__(512) void chunk_emb_kernel(
        const float* __restrict__ x, const float* __restrict__ w,
        uint4* __restrict__ emb16,
        const int* __restrict__ src, const int* __restrict__ dst,
        int* __restrict__ slots_lin,    // [NCH*CHUNK_E], pad-free
        int* __restrict__ cbase,        // [NCH][257] local run offsets
        int total8, int n_edges) {
    __shared__ int hist[256], base[256], cur[256];
    __shared__ int wsum[4];
    __shared__ int stage[CHUNK_E];      // 32 KB
    const int tid = threadIdx.x;
    const int lane = tid & 63, wid = tid >> 6;

    // ---- phase 0: emb16 = bf16(elu(x*w)), grid-stride ----
    if (tid < 256) hist[tid] = 0;
    const int gsz = gridDim.x * 512;
    for (int i = blockIdx.x * 512 + tid; i < total8; i += gsz) {
        f32x4 a = __builtin_nontemporal_load((const f32x4*)x + 2 * i);
        f32x4 b = __builtin_nontemporal_load((const f32x4*)x + 2 * i + 1);
        float4 wa = ((const float4*)w)[(2 * i) & 15];
        float4 wb = ((const float4*)w)[(2 * i + 1) & 15];
        uint4 o;
        o.x = bfpair(elu1(a.x * wa.x), elu1(a.y * wa.y));
        o.y = bfpair(elu1(a.z * wa.z), elu1(a.w * wa.w));
        o.z = bfpair(elu1(b.x * wb.x), elu1(b.y * wb.y));
        o.w = bfpair(elu1(b.z * wb.z), elu1(b.w * wb.w));
        emb16[i] = o;
    }

    // ---- chunk sort ----
    const int c0  = blockIdx.x * CHUNK_E;
    const int kn  = min(CHUNK_E, n_edges - c0);
    const int kn4 = kn >> 2;
    const int tail = kn & 3;
    __syncthreads();
    // pass 1: histogram by super-bucket (int4 loads)
    const int4* dst4 = (const int4*)(dst + c0);
    for (int k = tid; k < kn4; k += 512) {
        int4 dv = dst4[k];
        atomicAdd(&hist[dv.x >> SBSHIFT], 1);
        atomicAdd(&hist[dv.y >> SBSHIFT], 1);
        atomicAdd(&hist[dv.z >> SBSHIFT], 1);
        atomicAdd(&hist[dv.w >> SBSHIFT], 1);
    }
    if (tid < tail)
        atomicAdd(&hist[dst[c0 + (kn4 << 2) + tid] >> SBSHIFT], 1);
    __syncthreads();
    // exclusive scan of hist[0..256) on waves 0..3
    int h = 0, incl = 0;
    if (tid < 256) {
        h = hist[tid];
        incl = h;
        #pragma unroll
        for (int off = 1; off < 64; off <<= 1) {
            int t = __shfl_up(incl, off, 64);
            if (lane >= off) incl += t;
        }
        if (lane == 63) wsum[wid] = incl;
    }
    __syncthreads();
    if (tid < 256) {
        int pre = 0;
        for (int k = 0; k < wid; k++) pre += wsum[k];
        int e = pre + incl - h;
        base[tid] = e;
        cur[tid]  = e;
    }
    __syncthreads();
    // pass 2: scatter into LDS stage (edges L2-hot from pass 1)
    const int4* src4 = (const int4*)(src + c0);
    for (int k = tid; k < kn4; k += 512) {
        int4 dv = dst4[k];
        int4 sv = src4[k];
        int pos;
        pos = atomicAdd(&cur[dv.x >> SBSHIFT], 1);
        stage[pos] = ((dv.x & (SBROWS - 1)) << 17) | sv.x;
        pos = atomicAdd(&cur[dv.y >> SBSHIFT], 1);
        stage[pos] = ((dv.y & (SBROWS - 1)) << 17) | sv.y;
        pos = atomicAdd(&cur[dv.z >> SBSHIFT], 1);
        stage[pos] = ((dv.z & (SBROWS - 1)) << 17) | sv.z;
        pos = atomicAdd(&cur[dv.w >> SBSHIFT], 1);
        stage[pos] = ((dv.w & (SBROWS - 1)) << 17) | sv.w;
    }
    if (tid < tail) {
        int k = (kn4 << 2) + tid;
        int d = dst[c0 + k], s = src[c0 + k];
        int pos = atomicAdd(&cur[d >> SBSHIFT], 1);
        stage[pos] = ((d & (SBROWS - 1)) << 17) | s;
    }
    __syncthreads();
    // flush: fully coalesced linear copy, no padding, no partial lines
    for (int j = tid; j < kn; j += 512)
        slots_lin[c0 + j] = stage[j];
    if (tid < 256) cbase[blockIdx.x * 257 + tid] = base[tid];
    if (tid == 0)  cbase[blockIdx.x * 257 + 256] = kn;
}

// ---------- K2: per-sb LDS counting sort -> sorted2 + node_off.
//   sb_base computed INLINE: runs within a chunk are sb-ordered, so
//   sb_base(s) = sum_c cbase[c][s]  and  T = sum_c rc[c]  — both reductions
//   over values this kernel already loads.  16-lane subgroups process runs
//   (mean run ~42 edges -> 87% lane util vs 66% with 64-lane waves). ----
__global__ __launch_bounds__(512) void fine_sort_kernel(
        const int* __restrict__ slots_lin,
        const int* __restrict__ cbase,
        int* __restrict__ sorted2,
        int* __restrict__ node_off,
        int n_nodes, int NCH) {
    __shared__ int rstart[NCH_MAX], rc[NCH_MAX];
    __shared__ int counts[SBROWS], cur[SBROWS];
    __shared__ int wsum[8], swa[8], swt[8];
    __shared__ int stage_out[STAGE_CAP];   // 34.8 KB
    const int s = blockIdx.x;
    const int tid = threadIdx.x;           // 512
    const int wid = tid >> 6, lane = tid & 63;
    const int sg = tid >> 4, l16 = tid & 15;   // 32 subgroups of 16 lanes

    int va = 0, vt = 0;
    if (tid < NCH) {
        int a = cbase[tid * 257 + s];
        int b = cbase[tid * 257 + s + 1];
        rstart[tid] = tid * CHUNK_E + a;
        rc[tid] = b - a;
        va = a;
        vt = b - a;
    }
    // block-reduce va -> sbb, vt -> T
    #pragma unroll
    for (int off = 1; off < 64; off <<= 1) {
        va += __shfl_xor(va, off, 64);
        vt += __shfl_xor(vt, off, 64);
    }
    if (lane == 0) { swa[wid] = va; swt[wid] = vt; }
    counts[tid] = 0;                       // 512 threads cover SBROWS exactly
    __syncthreads();
    int sbb = 0, T = 0;
    #pragma unroll
    for (int k = 0; k < 8; k++) { sbb += swa[k]; T += swt[k]; }
    const bool fast = (T <= STAGE_CAP);
    // phase 1: histogram by local node (16-lane subgroups over runs)
    for (int c = sg; c < NCH; c += 32) {
        int n = rc[c], st = rstart[c];
        for (int j = l16; j < n; j += 16)
            atomicAdd(&counts[((unsigned)slots_lin[st + j]) >> 17], 1);
    }
    __syncthreads();
    // phase 2: exclusive scan of counts[512], one element per thread
    int v = counts[tid];
    int incl = v;
    #pragma unroll
    for (int off = 1; off < 64; off <<= 1) {
        int t = __shfl_up(incl, off, 64);
        if (lane >= off) incl += t;
    }
    if (lane == 63) wsum[wid] = incl;
    __syncthreads();
    int pre = 0;
    for (int k = 0; k < wid; k++) pre += wsum[k];
    int e0 = pre + incl - v;
    cur[tid] = fast ? e0 : sbb + e0;
    int g0 = (s << SBSHIFT) + tid;
    if (g0 < n_nodes) node_off[g0] = sbb + e0;
    if (s == gridDim.x - 1 && tid == 0) node_off[n_nodes] = sbb + T;
    __syncthreads();
    // phase 3: scatter (LDS stage fast path; direct global on skewed sb)
    for (int c = sg; c < NCH; c += 32) {
        int n = rc[c], st = rstart[c];
        for (int j = l16; j < n; j += 16) {
            int pl = slots_lin[st + j];
            int r = ((unsigned)pl) >> 17;
            int pos = atomicAdd(&cur[r], 1);
            if (fast) stage_out[pos] = pl & 0x1FFFF;
            else      sorted2[pos]   = pl & 0x1FFFF;
        }
    }
    __syncthreads();
    // phase 4: coalesced flush
    if (fast) {
        for (int i = tid; i < T; i += 512)
            sorted2[sbb + i] = stage_out[i];
    }
}

// ---------- K3: wave per node; coalesced index preload + shfl broadcast; up to
//               4 row-gathers in flight per group ----------
__global__ void gather_sum_kernel(const unsigned int* __restrict__ emb16,
                                  const int* __restrict__ sorted2,
                                  const int* __restrict__ node_off,
                                  float* __restrict__ out, int n_nodes) {
    int wave = (blockIdx.x * blockDim.x + threadIdx.x) >> 6;
    if (wave >= n_nodes) return;
    const int lane = threadIdx.x & 63;
    const int g = lane >> 3;          // 8 edge slots
    const int c = lane & 7;           // 8 int4-chunks per 128B row
    const int beg = node_off[wave], end = node_off[wave + 1];
    const int deg = end - beg;
    const int dmain = min(deg, 64);
    const int4* row = (const int4*)emb16;   // 8 int4 per row

    // one coalesced 64-lane load grabs this node's whole index list
    int myidx = 0;
    if (lane < dmain) myidx = __builtin_nontemporal_load(sorted2 + beg + lane);

    float acc[8] = {0.f, 0.f, 0.f, 0.f, 0.f, 0.f, 0.f, 0.f};

    for (int base = 0; base < dmain; base += 32) {
        const int m = dmain - base;   // edges remaining in this 32-round
        int s0 = __shfl(myidx, base + g, 64);
        int s1 = __shfl(myidx, base + g + 8, 64);
        int s2 = __shfl(myidx, base + g + 16, 64);
        int s3 = __shfl(myidx, base + g + 24, 64);
        int4 u0 = make_int4(0, 0, 0, 0);
        int4 u1 = make_int4(0, 0, 0, 0);
        int4 u2 = make_int4(0, 0, 0, 0);
        int4 u3 = make_int4(0, 0, 0, 0);
        // load phase: up to 4 independent gathers in flight per group
        if (g < m)      u0 = row[s0 * 8 + c];
        if (g + 8 < m)  u1 = row[s1 * 8 + c];
        if (g + 16 < m) u2 = row[s2 * 8 + c];
        if (g + 24 < m) u3 = row[s3 * 8 + c];
        // accumulate phase (zeros are numeric no-ops for masked slots)
        acc[0] += bl16(u0.x) + bl16(u1.x) + bl16(u2.x) + bl16(u3.x);
        acc[1] += bh16(u0.x) + bh16(u1.x) + bh16(u2.x) + bh16(u3.x);
        acc[2] += bl16(u0.y) + bl16(u1.y) + bl16(u2.y) + bl16(u3.y);
        acc[3] += bh16(u0.y) + bh16(u1.y) + bh16(u2.y) + bh16(u3.y);
        acc[4] += bl16(u0.z) + bl16(u1.z) + bl16(u2.z) + bl16(u3.z);
        acc[5] += bh16(u0.z) + bh16(u1.z) + bh16(u2.z) + bh16(u3.z);
        acc[6] += bl16(u0.w) + bl16(u1.w) + bl16(u2.w) + bl16(u3.w);
        acc[7] += bh16(u0.w) + bh16(u1.w) + bh16(u2.w) + bh16(u3.w);
    }
    // rare tail: deg > 64
    for (int e = beg + 64 + g; e < end; e += 8) {
        int s0 = __builtin_nontemporal_load(sorted2 + e);
        int4 u0 = row[s0 * 8 + c];
        acc[0] += bl16(u0.x); acc[1] += bh16(u0.x);
        acc[2] += bl16(u0.y); acc[3] += bh16(u0.y);
        acc[4] += bl16(u0.z); acc[5] += bh16(u0.z);
        acc[6] += bl16(u0.w); acc[7] += bh16(u0.w);
    }
    #pragma unroll
    for (int off = 8; off <= 32; off <<= 1) {
        #pragma unroll
        for (int k = 0; k < 8; k++) acc[k] += __shfl_xor(acc[k], off, 64);
    }
    if (g == 0) {
        f32x4* out4 = (f32x4*)out;
        f32x4 o0 = {acc[0], acc[1], acc[2], acc[3]};
        f32x4 o1 = {acc[4], acc[5], acc[6], acc[7]};
        __builtin_nontemporal_store(o0, out4 + wave * D4 + c * 2);
        __builtin_nontemporal_store(o1, out4 + wave * D4 + c * 2 + 1);
    }
}

// ---------- Fallback: atomic scatter ----------
__global__ void zero_out_kernel(float* __restrict__ out, int total4) {
    int i = blockIdx.x * blockDim.x + threadIdx.x;
    if (i < total4) ((float4*)out)[i] = make_float4(0.f, 0.f, 0.f, 0.f);
}

__global__ void scatter_fused_kernel(const float* __restrict__ x,
                                     const float* __restrict__ w,
                                     const int* __restrict__ src,
                                     const int* __restrict__ dst,
                                     float* __restrict__ out, int n_edges) {
    int t = blockIdx.x * blockDim.x + threadIdx.x;
    int e = t >> 4;
    int c = t & 15;
    if (e >= n_edges) return;
    int s = src[e];
    int d = dst[e];
    float4 xv = ((const float4*)x)[s * D4 + c];
    float4 wv = ((const float4*)w)[c];
    float* o = out + d * D + c * 4;
    unsafeAtomicAdd(o + 0, elu1(xv.x * wv.x));
    unsafeAtomicAdd(o + 1, elu1(xv.y * wv.y));
    unsafeAtomicAdd(o + 2, elu1(xv.z * wv.z));
    unsafeAtomicAdd(o + 3, elu1(xv.w * wv.w));
}

extern "C" void kernel_launch(void* const* d_in, const int* in_sizes, int n_in,
                              void* d_out, int out_size, void* d_ws, size_t ws_size,
                              hipStream_t stream) {
    const float* x   = (const float*)d_in[0];   // [N, 64] fp32
    const float* w   = (const float*)d_in[1];   // [1, 64] fp32
    const int*   src = (const int*)d_in[2];     // [E] int32
    const int*   dst = (const int*)d_in[3];     // [E] int32
    float* out = (float*)d_out;

    const int n_nodes = in_sizes[0] / D;
    const int n_edges = in_sizes[2];
    const int total4  = n_nodes * D4;
    const int total8  = n_nodes * 8;
    const int block = 256;

    const int NSB = (n_nodes + SBROWS - 1) >> SBSHIFT;
    const int NCH = (n_edges + CHUNK_E - 1) / CHUNK_E;

    auto align16 = [](size_t v) { return (v + 15) & ~size_t(15); };
    const size_t emb_b      = align16((size_t)n_nodes * D * 2);          // bf16
    const size_t slots_b    = align16((size_t)NCH * CHUNK_E * 4);
    const size_t cbase_b    = align16((size_t)NCH * 257 * 4);
    const size_t sorted2_b  = align16((size_t)n_edges * 4);
    const size_t nodeoff_b  = align16((size_t)(n_nodes + 1) * 4);
    const size_t need = emb_b + slots_b + cbase_b + sorted2_b + nodeoff_b;

    if (ws_size >= need && n_nodes <= 131072 && NSB <= NSB_MAX && NCH <= NCH_MAX) {
        char* p = (char*)d_ws;
        unsigned int* emb16 = (unsigned int*)p;  p += emb_b;
        int* slots_lin = (int*)p;  p += slots_b;
        int* cbase     = (int*)p;  p += cbase_b;
        int* sorted2   = (int*)p;  p += sorted2_b;
        int* node_off  = (int*)p;

        chunk_emb_kernel<<<NCH, 512, 0, stream>>>(
            x, w, (uint4*)emb16, src, dst, slots_lin, cbase, total8, n_edges);
        fine_sort_kernel<<<NSB, 512, 0, stream>>>(
            slots_lin, cbase, sorted2, node_off, n_nodes, NCH);
        const int wave_blocks = (n_nodes * 64 + block - 1) / block;
        gather_sum_kernel<<<wave_blocks, block, 0, stream>>>(
            emb16, sorted2, node_off, out, n_nodes);
    } else {
        zero_out_kernel<<<(total4 + block - 1) / block, block, 0, stream>>>(out, total4);
        const int nt = n_edges * 16;
        scatter_fused_kernel<<<(nt + block - 1) / block, block, 0, stream>>>(
            x, w, src, dst, out, n_edges);
    }
}

// Round 8
// 141.036 us; speedup vs baseline: 2.2833x; 1.0617x over previous
//
#include <hip/hip_runtime.h>

#define D 64
#define D4 (D / 4)         // 16 float4 per fp32 row
#define SBSHIFT 8          // 256 nodes per super-bucket
#define SBROWS 256
#define CHUNK_E 4096       // edges per chunk_sort block
#define STAGE_CAP 4608     // fine_sort staging entries (mean ~4092, +8 sigma)
#define NCH_MAX 512
#define NSB_MAX 512

typedef float f32x4 __attribute__((ext_vector_type(4)));

__device__ __forceinline__ float elu1(float z) {
    return z > 0.0f ? z : expm1f(z);
}

// pack two fp32 -> bf16 pair (RNE), a in low 16, b in high 16
__device__ __forceinline__ unsigned int bfpair(float a, float b) {
    unsigned int ua = __float_as_uint(a);
    unsigned int ub = __float_as_uint(b);
    ua = (ua + 0x7FFFu + ((ua >> 16) & 1u)) >> 16;
    ub = (ub + 0x7FFFu + ((ub >> 16) & 1u)) & 0xFFFF0000u;
    return ub | ua;
}

__device__ __forceinline__ float bl16(int u) {
    return __uint_as_float((unsigned)u << 16);
}
__device__ __forceinline__ float bh16(int u) {
    return __uint_as_float((unsigned)u & 0xFFFF0000u);
}

// ---------- K1: fused emb (grid-stride phase 0) + per-chunk LDS bucket sort ---
__global__ __launch_bounds__(512) void chunk_emb_kernel(
        const float* __restrict__ x, const float* __restrict__ w,
        uint4* __restrict__ emb16,
        const int* __restrict__ src, const int* __restrict__ dst,
        int* __restrict__ slots_lin,    // [NCH*CHUNK_E], pad-free
        int* __restrict__ cbase,        // [NCH][NSB+1] local run offsets
        int total8, int n_edges, int NSB) {
    __shared__ int hist[NSB_MAX], base[NSB_MAX], cur[NSB_MAX];
    __shared__ int wsum[8];
    __shared__ int stage[CHUNK_E];      // 16 KB
    const int tid = threadIdx.x;
    const int lane = tid & 63, wid = tid >> 6;

    // ---- phase 0: emb16 = bf16(elu(x*w)), grid-stride ----
    hist[tid] = 0;                      // 512 threads cover NSB_MAX exactly
    const int gsz = gridDim.x * 512;
    for (int i = blockIdx.x * 512 + tid; i < total8; i += gsz) {
        f32x4 a = __builtin_nontemporal_load((const f32x4*)x + 2 * i);
        f32x4 b = __builtin_nontemporal_load((const f32x4*)x + 2 * i + 1);
        float4 wa = ((const float4*)w)[(2 * i) & 15];
        float4 wb = ((const float4*)w)[(2 * i + 1) & 15];
        uint4 o;
        o.x = bfpair(elu1(a.x * wa.x), elu1(a.y * wa.y));
        o.y = bfpair(elu1(a.z * wa.z), elu1(a.w * wa.w));
        o.z = bfpair(elu1(b.x * wb.x), elu1(b.y * wb.y));
        o.w = bfpair(elu1(b.z * wb.z), elu1(b.w * wb.w));
        emb16[i] = o;
    }

    // ---- chunk sort ----
    const int c0  = blockIdx.x * CHUNK_E;
    const int kn  = min(CHUNK_E, n_edges - c0);
    const int kn4 = kn >> 2;
    const int tail = kn & 3;
    __syncthreads();
    // pass 1: histogram by super-bucket (int4 loads)
    const int4* dst4 = (const int4*)(dst + c0);
    for (int k = tid; k < kn4; k += 512) {
        int4 dv = dst4[k];
        atomicAdd(&hist[dv.x >> SBSHIFT], 1);
        atomicAdd(&hist[dv.y >> SBSHIFT], 1);
        atomicAdd(&hist[dv.z >> SBSHIFT], 1);
        atomicAdd(&hist[dv.w >> SBSHIFT], 1);
    }
    if (tid < tail)
        atomicAdd(&hist[dst[c0 + (kn4 << 2) + tid] >> SBSHIFT], 1);
    __syncthreads();
    // exclusive scan of hist[0..512), one element per thread (8 waves)
    int h = hist[tid];
    int incl = h;
    #pragma unroll
    for (int off = 1; off < 64; off <<= 1) {
        int t = __shfl_up(incl, off, 64);
        if (lane >= off) incl += t;
    }
    if (lane == 63) wsum[wid] = incl;
    __syncthreads();
    {
        int pre = 0;
        for (int k = 0; k < wid; k++) pre += wsum[k];
        int e = pre + incl - h;
        base[tid] = e;
        cur[tid]  = e;
    }
    __syncthreads();
    // pass 2: scatter into LDS stage (edges L2-hot from pass 1)
    const int4* src4 = (const int4*)(src + c0);
    for (int k = tid; k < kn4; k += 512) {
        int4 dv = dst4[k];
        int4 sv = src4[k];
        int pos;
        pos = atomicAdd(&cur[dv.x >> SBSHIFT], 1);
        stage[pos] = ((dv.x & (SBROWS - 1)) << 17) | sv.x;
        pos = atomicAdd(&cur[dv.y >> SBSHIFT], 1);
        stage[pos] = ((dv.y & (SBROWS - 1)) << 17) | sv.y;
        pos = atomicAdd(&cur[dv.z >> SBSHIFT], 1);
        stage[pos] = ((dv.z & (SBROWS - 1)) << 17) | sv.z;
        pos = atomicAdd(&cur[dv.w >> SBSHIFT], 1);
        stage[pos] = ((dv.w & (SBROWS - 1)) << 17) | sv.w;
    }
    if (tid < tail) {
        int k = (kn4 << 2) + tid;
        int d = dst[c0 + k], s = src[c0 + k];
        int pos = atomicAdd(&cur[d >> SBSHIFT], 1);
        stage[pos] = ((d & (SBROWS - 1)) << 17) | s;
    }
    __syncthreads();
    // flush: fully coalesced linear copy
    for (int j = tid; j < kn; j += 512)
        slots_lin[c0 + j] = stage[j];
    if (tid < NSB) cbase[blockIdx.x * (NSB + 1) + tid] = base[tid];
    if (tid == 0)  cbase[blockIdx.x * (NSB + 1) + NSB] = kn;
}

// ---------- K2: per-sb LDS counting sort -> sorted2 + node_off.
//   sb_base computed INLINE: sb_base(s) = sum_c cbase[c][s], T = sum_c rc[c].
//   16-lane subgroups process runs. ----
__global__ __launch_bounds__(512) void fine_sort_kernel(
        const int* __restrict__ slots_lin,
        const int* __restrict__ cbase,
        int* __restrict__ sorted2,
        int* __restrict__ node_off,
        int n_nodes, int NCH, int NSB) {
    __shared__ int rstart[NCH_MAX], rc[NCH_MAX];
    __shared__ int counts[SBROWS], cur[SBROWS];
    __shared__ int wsum[4], swa[8], swt[8];
    __shared__ int stage_out[STAGE_CAP];   // 18 KB
    const int s = blockIdx.x;
    const int tid = threadIdx.x;           // 512
    const int wid = tid >> 6, lane = tid & 63;
    const int sg = tid >> 4, l16 = tid & 15;   // 32 subgroups of 16 lanes

    int va = 0, vt = 0;
    if (tid < NCH) {
        int a = cbase[tid * (NSB + 1) + s];
        int b = cbase[tid * (NSB + 1) + s + 1];
        rstart[tid] = tid * CHUNK_E + a;
        rc[tid] = b - a;
        va = a;
        vt = b - a;
    }
    // block-reduce va -> sbb, vt -> T
    #pragma unroll
    for (int off = 1; off < 64; off <<= 1) {
        va += __shfl_xor(va, off, 64);
        vt += __shfl_xor(vt, off, 64);
    }
    if (lane == 0) { swa[wid] = va; swt[wid] = vt; }
    if (tid < SBROWS) counts[tid] = 0;
    __syncthreads();
    int sbb = 0, T = 0;
    #pragma unroll
    for (int k = 0; k < 8; k++) { sbb += swa[k]; T += swt[k]; }
    const bool fast = (T <= STAGE_CAP);
    // phase 1: histogram by local node (16-lane subgroups over runs)
    for (int c = sg; c < NCH; c += 32) {
        int n = rc[c], st = rstart[c];
        for (int j = l16; j < n; j += 16)
            atomicAdd(&counts[((unsigned)slots_lin[st + j]) >> 17], 1);
    }
    __syncthreads();
    // phase 2: exclusive scan of counts[256] (4 waves)
    int v = 0, incl = 0;
    if (tid < SBROWS) {
        v = counts[tid];
        incl = v;
        #pragma unroll
        for (int off = 1; off < 64; off <<= 1) {
            int t = __shfl_up(incl, off, 64);
            if (lane >= off) incl += t;
        }
        if (lane == 63) wsum[wid] = incl;
    }
    __syncthreads();
    if (tid < SBROWS) {
        int pre = 0;
        for (int k = 0; k < wid; k++) pre += wsum[k];
        int e0 = pre + incl - v;
        cur[tid] = fast ? e0 : sbb + e0;
        int g0 = (s << SBSHIFT) + tid;
        if (g0 < n_nodes) node_off[g0] = sbb + e0;
    }
    if (s == gridDim.x - 1 && tid == 0) node_off[n_nodes] = sbb + T;
    __syncthreads();
    // phase 3: scatter (LDS stage fast path; direct global on skewed sb)
    for (int c = sg; c < NCH; c += 32) {
        int n = rc[c], st = rstart[c];
        for (int j = l16; j < n; j += 16) {
            int pl = slots_lin[st + j];
            int r = ((unsigned)pl) >> 17;
            int pos = atomicAdd(&cur[r], 1);
            if (fast) stage_out[pos] = pl & 0x1FFFF;
            else      sorted2[pos]   = pl & 0x1FFFF;
        }
    }
    __syncthreads();
    // phase 4: coalesced flush
    if (fast) {
        for (int i = tid; i < T; i += 512)
            sorted2[sbb + i] = stage_out[i];
    }
}

// ---------- K3: 8 nodes per wave, 8 lanes per node.  Lane-local accumulation.
//   CORRECTNESS INVARIANT: every __shfl executes with ALL 64 lanes active —
//   loop bound is the wave-uniform dmax (max over the 8 node groups), window
//   position p clamped to [0, T-1]; only the row-load+accumulate is
//   predicated on e < d. ----------
__device__ __forceinline__ int pick_idx(int p, int m0, int m1, int m2,
                                        const int* __restrict__ s2, int W0) {
    int a  = __shfl(m0, p & 63, 64);
    int b  = __shfl(m1, p & 63, 64);
    int cc = __shfl(m2, p & 63, 64);
    int r = p < 64 ? a : (p < 128 ? b : cc);
    if (p >= 192) r = s2[W0 + p];   // rare overflow, p < T so in range
    return r;
}

__global__ void gather_sum_kernel(const unsigned int* __restrict__ emb16,
                                  const int* __restrict__ sorted2,
                                  const int* __restrict__ node_off,
                                  float* __restrict__ out, int n_nodes) {
    const int wv = (blockIdx.x * blockDim.x + threadIdx.x) >> 6;
    const int lane = threadIdx.x & 63;
    const int g = lane >> 3;          // node slot within wave (8 nodes/wave)
    const int c = lane & 7;           // int4 chunk within 128B row
    const int n0 = wv * 8;
    if (n0 >= n_nodes) return;        // wave-uniform exit
    const int n = n0 + g;

    int beg = 0, end = 0;
    if (n < n_nodes) {
        beg = node_off[n];
        end = node_off[n + 1];
    }
    const int W0   = node_off[n0];                        // broadcast load
    const int Wend = node_off[min(n0 + 8, n_nodes)];      // broadcast load
    const int T = Wend - W0;

    // coalesced preload of the wave's contiguous edge window (up to 192)
    int m0 = 0, m1 = 0, m2 = 0;
    if (lane < T)       m0 = sorted2[W0 + lane];
    if (64 + lane < T)  m1 = sorted2[W0 + 64 + lane];
    if (128 + lane < T) m2 = sorted2[W0 + 128 + lane];

    const int4* row = (const int4*)emb16;   // 8 int4 per row
    const int pb = beg - W0;
    const int d = end - beg;
    // wave-uniform trip count: max degree over the 8 groups (d uniform in-group)
    int dmax = d;
    dmax = max(dmax, __shfl_xor(dmax, 8, 64));
    dmax = max(dmax, __shfl_xor(dmax, 16, 64));
    dmax = max(dmax, __shfl_xor(dmax, 32, 64));
    const int pclamp = T - 1;

    float acc[8] = {0.f, 0.f, 0.f, 0.f, 0.f, 0.f, 0.f, 0.f};

    int e = 0;
    for (; e + 4 <= dmax; e += 4) {
        int p0 = min(max(pb + e,     0), pclamp);
        int p1 = min(max(pb + e + 1, 0), pclamp);
        int p2 = min(max(pb + e + 2, 0), pclamp);
        int p3 = min(max(pb + e + 3, 0), pclamp);
        int i0 = pick_idx(p0, m0, m1, m2, sorted2, W0);
        int i1 = pick_idx(p1, m0, m1, m2, sorted2, W0);
        int i2 = pick_idx(p2, m0, m1, m2, sorted2, W0);
        int i3 = pick_idx(p3, m0, m1, m2, sorted2, W0);
        int4 u0 = make_int4(0, 0, 0, 0);
        int4 u1 = make_int4(0, 0, 0, 0);
        int4 u2 = make_int4(0, 0, 0, 0);
        int4 u3 = make_int4(0, 0, 0, 0);
        if (e < d)     u0 = row[i0 * 8 + c];
        if (e + 1 < d) u1 = row[i1 * 8 + c];
        if (e + 2 < d) u2 = row[i2 * 8 + c];
        if (e + 3 < d) u3 = row[i3 * 8 + c];
        acc[0] += bl16(u0.x) + bl16(u1.x) + bl16(u2.x) + bl16(u3.x);
        acc[1] += bh16(u0.x) + bh16(u1.x) + bh16(u2.x) + bh16(u3.x);
        acc[2] += bl16(u0.y) + bl16(u1.y) + bl16(u2.y) + bl16(u3.y);
        acc[3] += bh16(u0.y) + bh16(u1.y) + bh16(u2.y) + bh16(u3.y);
        acc[4] += bl16(u0.z) + bl16(u1.z) + bl16(u2.z) + bl16(u3.z);
        acc[5] += bh16(u0.z) + bh16(u1.z) + bh16(u2.z) + bh16(u3.z);
        acc[6] += bl16(u0.w) + bl16(u1.w) + bl16(u2.w) + bl16(u3.w);
        acc[7] += bh16(u0.w) + bh16(u1.w) + bh16(u2.w) + bh16(u3.w);
    }
    for (; e < dmax; ++e) {
        int p0 = min(max(pb + e, 0), pclamp);
        int i0 = pick_idx(p0, m0, m1, m2, sorted2, W0);
        if (e < d) {
            int4 u0 = row[i0 * 8 + c];
            acc[0] += bl16(u0.x); acc[1] += bh16(u0.x);
            acc[2] += bl16(u0.y); acc[3] += bh16(u0.y);
            acc[4] += bl16(u0.z); acc[5] += bh16(u0.z);
            acc[6] += bl16(u0.w); acc[7] += bh16(u0.w);
        }
    }

    if (n < n_nodes) {
        f32x4* out4 = (f32x4*)out;
        f32x4 o0 = {acc[0], acc[1], acc[2], acc[3]};
        f32x4 o1 = {acc[4], acc[5], acc[6], acc[7]};
        __builtin_nontemporal_store(o0, out4 + (size_t)n * D4 + c * 2);
        __builtin_nontemporal_store(o1, out4 + (size_t)n * D4 + c * 2 + 1);
    }
}

// ---------- Fallback: atomic scatter ----------
__global__ void zero_out_kernel(float* __restrict__ out, int total4) {
    int i = blockIdx.x * blockDim.x + threadIdx.x;
    if (i < total4) ((float4*)out)[i] = make_float4(0.f, 0.f, 0.f, 0.f);
}

__global__ void scatter_fused_kernel(const float* __restrict__ x,
                                     const float* __restrict__ w,
                                     const int* __restrict__ src,
                                     const int* __restrict__ dst,
                                     float* __restrict__ out, int n_edges) {
    int t = blockIdx.x * blockDim.x + threadIdx.x;
    int e = t >> 4;
    int c = t & 15;
    if (e >= n_edges) return;
    int s = src[e];
    int d = dst[e];
    float4 xv = ((const float4*)x)[s * D4 + c];
    float4 wv = ((const float4*)w)[c];
    float* o = out + d * D + c * 4;
    unsafeAtomicAdd(o + 0, elu1(xv.x * wv.x));
    unsafeAtomicAdd(o + 1, elu1(xv.y * wv.y));
    unsafeAtomicAdd(o + 2, elu1(xv.z * wv.z));
    unsafeAtomicAdd(o + 3, elu1(xv.w * wv.w));
}

extern "C" void kernel_launch(void* const* d_in, const int* in_sizes, int n_in,
                              void* d_out, int out_size, void* d_ws, size_t ws_size,
                              hipStream_t stream) {
    const float* x   = (const float*)d_in[0];   // [N, 64] fp32
    const float* w   = (const float*)d_in[1];   // [1, 64] fp32
    const int*   src = (const int*)d_in[2];     // [E] int32
    const int*   dst = (const int*)d_in[3];     // [E] int32
    float* out = (float*)d_out;

    const int n_nodes = in_sizes[0] / D;
    const int n_edges = in_sizes[2];
    const int total4  = n_nodes * D4;
    const int total8  = n_nodes * 8;
    const int block = 256;

    const int NSB = (n_nodes + SBROWS - 1) >> SBSHIFT;
    const int NCH = (n_edges + CHUNK_E - 1) / CHUNK_E;

    auto align16 = [](size_t v) { return (v + 15) & ~size_t(15); };
    const size_t emb_b      = align16((size_t)n_nodes * D * 2);          // bf16
    const size_t slots_b    = align16((size_t)NCH * CHUNK_E * 4);
    const size_t cbase_b    = align16((size_t)NCH * (NSB + 1) * 4);
    const size_t sorted2_b  = align16((size_t)n_edges * 4);
    const size_t nodeoff_b  = align16((size_t)(n_nodes + 1) * 4);
    const size_t need = emb_b + slots_b + cbase_b + sorted2_b + nodeoff_b;

    if (ws_size >= need && n_nodes <= 131072 && NSB <= NSB_MAX && NCH <= NCH_MAX) {
        char* p = (char*)d_ws;
        unsigned int* emb16 = (unsigned int*)p;  p += emb_b;
        int* slots_lin = (int*)p;  p += slots_b;
        int* cbase     = (int*)p;  p += cbase_b;
        int* sorted2   = (int*)p;  p += sorted2_b;
        int* node_off  = (int*)p;

        chunk_emb_kernel<<<NCH, 512, 0, stream>>>(
            x, w, (uint4*)emb16, src, dst, slots_lin, cbase,
            total8, n_edges, NSB);
        fine_sort_kernel<<<NSB, 512, 0, stream>>>(
            slots_lin, cbase, sorted2, node_off, n_nodes, NCH, NSB);
        const int nwaves = (n_nodes + 7) / 8;
        const int gblocks = (nwaves * 64 + block - 1) / block;
        gather_sum_kernel<<<gblocks, block, 0, stream>>>(
            emb16, sorted2, node_off, out, n_nodes);
    } else {
        zero_out_kernel<<<(total4 + block - 1) / block, block, 0, stream>>>(out, total4);
        const int nt = n_edges * 16;
        scatter_fused_kernel<<<(nt + block - 1) / block, block, 0, stream>>>(
            x, w, src, dst, out, n_edges);
    }
}